// Round 1
// baseline (589.706 us; speedup 1.0000x reference)
//
#include <hip/hip_runtime.h>
#include <math.h>
#include <stdint.h>

#define BB   4
#define QQ   200
#define NGT  32
#define DD   65536   // 256*256
#define TOPK 4
#define EPSF 1e-6f

// ---------------------------------------------------------------------------
// K1: bit-pack gt_masks [B,N,D] (binary f32) -> packed[b][d] uint32 (bit n = gt[b,n,d])
// 256 blocks (64 per batch), each thread packs 4 consecutive pixels via float4 loads.
__global__ __launch_bounds__(256) void k_pack(const float* __restrict__ gt,
                                              uint32_t* __restrict__ packed) {
    int blk = blockIdx.x;
    int b = blk >> 6;                              // 64 blocks per batch
    int d0 = ((blk & 63) * 256 + threadIdx.x) * 4; // 4 pixels per thread
    uint32_t px = 0, py = 0, pz = 0, pw = 0;
    const float* gb = gt + (size_t)b * NGT * DD + d0;
#pragma unroll
    for (int n = 0; n < NGT; ++n) {
        float4 g = *(const float4*)(gb + (size_t)n * DD);
        px |= (g.x > 0.5f ? 1u : 0u) << n;
        py |= (g.y > 0.5f ? 1u : 0u) << n;
        pz |= (g.z > 0.5f ? 1u : 0u) << n;
        pw |= (g.w > 0.5f ? 1u : 0u) << n;
    }
    *(uint4*)(packed + (size_t)b * DD + d0) = make_uint4(px, py, pz, pw);
}

// ---------------------------------------------------------------------------
// K2: tsum[b][n] = sum_d gt[b,n,d], computed by popcounting the packed bits.
// One block per (b,n); packed slab (256 KB) is L2-resident.
__global__ __launch_bounds__(256) void k_tsum(const uint32_t* __restrict__ packed,
                                              float* __restrict__ tsum) {
    int b = blockIdx.x >> 5;
    int n = blockIdx.x & 31;
    const uint4* pp = (const uint4*)(packed + (size_t)b * DD);
    int cnt = 0;
    for (int i = threadIdx.x; i < DD / 4; i += 256) {
        uint4 w = pp[i];
        cnt += (int)((w.x >> n) & 1u) + (int)((w.y >> n) & 1u) +
               (int)((w.z >> n) & 1u) + (int)((w.w >> n) & 1u);
    }
#pragma unroll
    for (int off = 32; off; off >>= 1) cnt += __shfl_xor(cnt, off);
    __shared__ int red[4];
    if ((threadIdx.x & 63) == 0) red[threadIdx.x >> 6] = cnt;
    __syncthreads();
    if (threadIdx.x == 0)
        tsum[blockIdx.x] = (float)(red[0] + red[1] + red[2] + red[3]);
}

// ---------------------------------------------------------------------------
// K3: cls[b][q] = softmax(pred_logits)[...,1] = sigmoid(l1 - l0)
__global__ __launch_bounds__(256) void k_cls(const float* __restrict__ logits,
                                             float* __restrict__ cls) {
    int i = blockIdx.x * 256 + threadIdx.x;
    if (i < BB * QQ) {
        float l0 = logits[2 * i], l1 = logits[2 * i + 1];
        cls[i] = 1.0f / (1.0f + expf(l0 - l1));
    }
}

// ---------------------------------------------------------------------------
// K4: main — one block per (b,q). Streams pred_masks once; for each pixel,
// sigmoid then 32 masked accumulations using the sign-extended-bit AND trick.
// Writes combined[b][n][q] = iou * cls.
__global__ __launch_bounds__(256) void k_main(const float* __restrict__ pm,
                                              const uint32_t* __restrict__ packed,
                                              const float* __restrict__ tsum,
                                              const float* __restrict__ cls,
                                              float* __restrict__ combined) {
    int b = blockIdx.x / QQ;
    int q = blockIdx.x % QQ;
    const float4* pm4 = (const float4*)(pm + (size_t)(b * QQ + q) * DD);
    const uint4*  mp4 = (const uint4*)(packed + (size_t)b * DD);

    float acc[NGT];
#pragma unroll
    for (int n = 0; n < NGT; ++n) acc[n] = 0.0f;
    float psum = 0.0f;

    for (int it = 0; it < DD / 4 / 256; ++it) {   // 64 iterations
        int i = it * 256 + threadIdx.x;
        float4 x = pm4[i];
        uint4  m = mp4[i];
        {
            float s = 1.0f / (1.0f + expf(-x.x)); psum += s;
            int si = __float_as_int(s); uint32_t mm = m.x;
#pragma unroll
            for (int n = 0; n < NGT; ++n)
                acc[n] += __int_as_float(si & ((int)(mm << (31 - n)) >> 31));
        }
        {
            float s = 1.0f / (1.0f + expf(-x.y)); psum += s;
            int si = __float_as_int(s); uint32_t mm = m.y;
#pragma unroll
            for (int n = 0; n < NGT; ++n)
                acc[n] += __int_as_float(si & ((int)(mm << (31 - n)) >> 31));
        }
        {
            float s = 1.0f / (1.0f + expf(-x.z)); psum += s;
            int si = __float_as_int(s); uint32_t mm = m.z;
#pragma unroll
            for (int n = 0; n < NGT; ++n)
                acc[n] += __int_as_float(si & ((int)(mm << (31 - n)) >> 31));
        }
        {
            float s = 1.0f / (1.0f + expf(-x.w)); psum += s;
            int si = __float_as_int(s); uint32_t mm = m.w;
#pragma unroll
            for (int n = 0; n < NGT; ++n)
                acc[n] += __int_as_float(si & ((int)(mm << (31 - n)) >> 31));
        }
    }

    // wave butterfly reduce (64 lanes), then cross-wave via LDS
#pragma unroll
    for (int off = 32; off; off >>= 1) {
        psum += __shfl_xor(psum, off);
#pragma unroll
        for (int n = 0; n < NGT; ++n) acc[n] += __shfl_xor(acc[n], off);
    }
    __shared__ float red[4][NGT + 1];
    int lane = threadIdx.x & 63, w = threadIdx.x >> 6;
    if (lane == 0) {
#pragma unroll
        for (int n = 0; n < NGT; ++n) red[w][n] = acc[n];
        red[w][NGT] = psum;
    }
    __syncthreads();
    __shared__ float fin[NGT + 1];
    if (threadIdx.x < NGT + 1)
        fin[threadIdx.x] = red[0][threadIdx.x] + red[1][threadIdx.x] +
                           red[2][threadIdx.x] + red[3][threadIdx.x];
    __syncthreads();
    if (threadIdx.x < NGT) {
        float inter = fin[threadIdx.x];
        float un    = fin[NGT] + tsum[b * NGT + threadIdx.x] - inter;
        float iou   = inter / (un + EPSF);
        combined[(size_t)(b * NGT + threadIdx.x) * QQ + q] = iou * cls[b * QQ + q];
    }
}

// ---------------------------------------------------------------------------
// K5: greedy per-GT top-4 with dedup. One wave per batch; no barriers.
// Matches jax.lax.top_k tie-break (lower index first).
__global__ __launch_bounds__(64) void k_greedy(const float* __restrict__ combined,
                                               int* __restrict__ out) {
    int b = blockIdx.x;
    int lane = threadIdx.x;
    const float* cb = combined + (size_t)b * NGT * QQ;
    int* src = out;
    int* tgt = out + BB * NGT * TOPK;
    int* val = out + 2 * BB * NGT * TOPK;

    int asg = 0;  // assigned bits for q = lane + 64*slot
    for (int n = 0; n < NGT; ++n) {
        float v[4];
#pragma unroll
        for (int s = 0; s < 4; ++s) {
            int q = lane + 64 * s;
            v[s] = (q < QQ) ? cb[n * QQ + q] : -INFINITY;
        }
        for (int k = 0; k < TOPK; ++k) {
            // lane-local best (strict > keeps lowest index on ties)
            float bv = -INFINITY;
            int   bi = 0x7fffffff;
#pragma unroll
            for (int s = 0; s < 4; ++s)
                if (v[s] > bv) { bv = v[s]; bi = lane + 64 * s; }
            // wave butterfly argmax, lexicographic (value desc, index asc)
#pragma unroll
            for (int off = 32; off; off >>= 1) {
                float ov = __shfl_xor(bv, off);
                int   oi = __shfl_xor(bi, off);
                if (ov > bv || (ov == bv && oi < bi)) { bv = ov; bi = oi; }
            }
            int owner = bi & 63, slot = bi >> 6;
            int oasg  = __shfl(asg, owner);
            int taken = (oasg >> slot) & 1;
#pragma unroll
            for (int s = 0; s < 4; ++s)
                if (lane == owner && s == slot) v[s] = -INFINITY;
            if (lane == owner) asg |= (1 << slot);
            if (lane == 0) {
                int o = (b * NGT + n) * TOPK + k;
                src[o] = taken ? -1 : bi;
                tgt[o] = taken ? -1 : n;
                val[o] = taken ? 0 : 1;
            }
        }
    }
}

// ---------------------------------------------------------------------------
extern "C" void kernel_launch(void* const* d_in, const int* in_sizes, int n_in,
                              void* d_out, int out_size, void* d_ws, size_t ws_size,
                              hipStream_t stream) {
    const float* pred_masks  = (const float*)d_in[0];  // [4,200,256,256]
    const float* pred_logits = (const float*)d_in[1];  // [4,200,2]
    const float* gt_masks    = (const float*)d_in[2];  // [4,32,256,256]

    uint8_t* ws = (uint8_t*)d_ws;
    uint32_t* packed  = (uint32_t*)ws;                                  // 1 MB
    float*    tsum    = (float*)(ws + (size_t)BB * DD * sizeof(uint32_t)); // 512 B
    float*    cls     = tsum + BB * NGT;                                // 3.2 KB
    float*    combined = cls + BB * QQ;                                 // 102.4 KB

    k_pack<<<BB * (DD / 1024), 256, 0, stream>>>(gt_masks, packed);
    k_tsum<<<BB * NGT, 256, 0, stream>>>(packed, tsum);
    k_cls<<<(BB * QQ + 255) / 256, 256, 0, stream>>>(pred_logits, cls);
    k_main<<<BB * QQ, 256, 0, stream>>>(pred_masks, packed, tsum, cls, combined);
    k_greedy<<<BB, 64, 0, stream>>>(combined, (int*)d_out);
}

// Round 2
// 482.219 us; speedup vs baseline: 1.2229x; 1.2229x over previous
//
#include <hip/hip_runtime.h>
#include <math.h>
#include <stdint.h>

#define BB    4
#define QQ    200
#define NGT   32
#define DD    65536   // 256*256
#define TOPK  4
#define EPSF  1e-6f

#define QT_   13      // ceil(200/16) q-tiles of 16
#define QP    208     // padded Q stride
#define KSPLIT 32     // K-split workgroups per (b, qtile)
#define KC    (DD / KSPLIT)   // 2048 k per workgroup
#define BK    256     // staged K chunk
#define BKP   264     // +8 ushort pad (16B) -> 2-way-max LDS bank aliasing on b128 reads

typedef float  f32x4  __attribute__((ext_vector_type(4)));
typedef __bf16 bf16x8 __attribute__((ext_vector_type(8)));

// ---------------------------------------------------------------------------
// K1: bit-pack gt_masks [B,N,D] (binary f32) -> packed[b][d] uint32 (bit n = gt[b,n,d])
__global__ __launch_bounds__(256) void k_pack(const float* __restrict__ gt,
                                              uint32_t* __restrict__ packed) {
    int blk = blockIdx.x;
    int b = blk >> 6;                              // 64 blocks per batch
    int d0 = ((blk & 63) * 256 + threadIdx.x) * 4; // 4 pixels per thread
    uint32_t px = 0, py = 0, pz = 0, pw = 0;
    const float* gb = gt + (size_t)b * NGT * DD + d0;
#pragma unroll
    for (int n = 0; n < NGT; ++n) {
        float4 g = *(const float4*)(gb + (size_t)n * DD);
        px |= (g.x > 0.5f ? 1u : 0u) << n;
        py |= (g.y > 0.5f ? 1u : 0u) << n;
        pz |= (g.z > 0.5f ? 1u : 0u) << n;
        pw |= (g.w > 0.5f ? 1u : 0u) << n;
    }
    *(uint4*)(packed + (size_t)b * DD + d0) = make_uint4(px, py, pz, pw);
}

// ---------------------------------------------------------------------------
// K2: tsum[b][n] via popcount of packed bits; ALSO zero-inits inter+psum
// (ws is poisoned 0xAA before every call) and computes cls (softmax[...,1]).
__global__ __launch_bounds__(256) void k_tsum(const uint32_t* __restrict__ packed,
                                              float* __restrict__ tsum,
                                              float* __restrict__ zero_base,  // inter(26624)+psum(832)
                                              const float* __restrict__ logits,
                                              float* __restrict__ cls) {
    // fused zero-init: 128 blocks x 256 threads covers 27456 floats
    int zidx = blockIdx.x * 256 + threadIdx.x;
    if (zidx < BB * NGT * QP + BB * QP) zero_base[zidx] = 0.0f;
    // fused cls: blocks 0..3
    if (blockIdx.x < 4) {
        int i = blockIdx.x * 256 + threadIdx.x;
        if (i < BB * QQ) {
            float l0 = logits[2 * i], l1 = logits[2 * i + 1];
            cls[i] = 1.0f / (1.0f + expf(l0 - l1));
        }
    }
    int b = blockIdx.x >> 5;
    int n = blockIdx.x & 31;
    const uint4* pp = (const uint4*)(packed + (size_t)b * DD);
    int cnt = 0;
    for (int i = threadIdx.x; i < DD / 4; i += 256) {
        uint4 w = pp[i];
        cnt += (int)((w.x >> n) & 1u) + (int)((w.y >> n) & 1u) +
               (int)((w.z >> n) & 1u) + (int)((w.w >> n) & 1u);
    }
#pragma unroll
    for (int off = 32; off; off >>= 1) cnt += __shfl_xor(cnt, off);
    __shared__ int red[4];
    if ((threadIdx.x & 63) == 0) red[threadIdx.x >> 6] = cnt;
    __syncthreads();
    if (threadIdx.x == 0)
        tsum[blockIdx.x] = (float)(red[0] + red[1] + red[2] + red[3]);
}

// ---------------------------------------------------------------------------
// K3: MFMA main. Grid = B * QT_ * KSPLIT workgroups of 256 (4 waves).
// Each wg: 16-q tile, 2048-k chunk. A = sigmoid(pm) split EXACTLY into 3 bf16
// terms (hi/mid/lo cover mantissa bits 1-8/9-16/17-24); B = gt bits as bf16
// 0/1 built on the fly from packed words. 6 mfma_f32_16x16x32_bf16 per 32-k
// step (3 terms x 2 n-tiles). Partial C + psum -> fp32 atomicAdd.
__global__ __launch_bounds__(256) void k_mfma(const float* __restrict__ pm,
                                              const uint32_t* __restrict__ packed,
                                              float* __restrict__ inter,   // [B][32][QP]
                                              float* __restrict__ psum) {  // [B][QP]
    int blk = blockIdx.x;
    int b   = blk / (QT_ * KSPLIT);
    int rem = blk % (QT_ * KSPLIT);
    int qt  = rem / KSPLIT;
    int ks  = rem % KSPLIT;
    int tid = threadIdx.x;
    int lane = tid & 63, wave = tid >> 6;

    __shared__ __bf16 a_h[16][BKP];
    __shared__ __bf16 a_m[16][BKP];
    __shared__ __bf16 a_l[16][BKP];

    // staging role: thread t loads pm[q = t>>4][dseg = (t&15)*16 .. +16)
    int q_local = tid >> 4;
    int dseg    = (tid & 15) * 16;
    int q_glob  = qt * 16 + q_local;
    int q_eff   = q_glob < QQ ? q_glob : QQ - 1;   // clamp padded rows
    const float*    pmrow = pm + (size_t)(b * QQ + q_eff) * DD + ks * KC;
    const uint32_t* pk    = packed + (size_t)b * DD + ks * KC;

    // compute role
    int m    = lane & 15;      // A row / C col-select
    int quad = lane >> 4;

    f32x4 c0 = {0.f, 0.f, 0.f, 0.f};
    f32x4 c1 = {0.f, 0.f, 0.f, 0.f};
    float ps = 0.f;

    for (int ch = 0; ch < KC / BK; ++ch) {   // 8 chunks of 256 k
        // ---- stage: 16 floats/thread -> sigmoid -> 3-way exact bf16 split
        const float* src = pmrow + ch * BK + dseg;
        bf16x8 h[2], md[2], lo[2];
#pragma unroll
        for (int g = 0; g < 2; ++g) {
            float4 f0 = *(const float4*)(src + g * 8);
            float4 f1 = *(const float4*)(src + g * 8 + 4);
            float v[8] = {f0.x, f0.y, f0.z, f0.w, f1.x, f1.y, f1.z, f1.w};
#pragma unroll
            for (int i = 0; i < 8; ++i) {
                float s  = 1.0f / (1.0f + expf(-v[i]));
                ps += s;
                __bf16 hh = (__bf16)s;
                float  r1 = s - (float)hh;        // exact
                __bf16 mm = (__bf16)r1;
                float  r2 = r1 - (float)mm;       // exact
                __bf16 ll = (__bf16)r2;           // exact (<=8 significant bits left)
                h[g][i] = hh; md[g][i] = mm; lo[g][i] = ll;
            }
        }
        __syncthreads();   // previous chunk's reads done before overwrite
        *(bf16x8*)&a_h[q_local][dseg]     = h[0];
        *(bf16x8*)&a_h[q_local][dseg + 8] = h[1];
        *(bf16x8*)&a_m[q_local][dseg]     = md[0];
        *(bf16x8*)&a_m[q_local][dseg + 8] = md[1];
        *(bf16x8*)&a_l[q_local][dseg]     = lo[0];
        *(bf16x8*)&a_l[q_local][dseg + 8] = lo[1];
        __syncthreads();

        // ---- compute: wave w takes 32-k steps {2w, 2w+1} of this chunk
#pragma unroll
        for (int st = 0; st < 2; ++st) {
            int k0 = (wave * 2 + st) * 32;
            bf16x8 ah = *(const bf16x8*)&a_h[m][k0 + quad * 8];
            bf16x8 am = *(const bf16x8*)&a_m[m][k0 + quad * 8];
            bf16x8 al = *(const bf16x8*)&a_l[m][k0 + quad * 8];
            const uint32_t* pw = pk + ch * BK + k0 + quad * 8;
            uint4 w0 = *(const uint4*)(pw);
            uint4 w1 = *(const uint4*)(pw + 4);
            uint32_t wj[8] = {w0.x, w0.y, w0.z, w0.w, w1.x, w1.y, w1.z, w1.w};
            union { ushort u[8]; bf16x8 v; } b0, b1;
#pragma unroll
            for (int j = 0; j < 8; ++j) {
                // sbfe(bit) & 0x3F80 -> bf16 1.0 or 0.0
                b0.u[j] = (ushort)(((int)(wj[j] << (31 - m)) >> 31) & 0x3F80);
                b1.u[j] = (ushort)(((int)(wj[j] << (15 - m)) >> 31) & 0x3F80);
            }
            c0 = __builtin_amdgcn_mfma_f32_16x16x32_bf16(ah, b0.v, c0, 0, 0, 0);
            c0 = __builtin_amdgcn_mfma_f32_16x16x32_bf16(am, b0.v, c0, 0, 0, 0);
            c0 = __builtin_amdgcn_mfma_f32_16x16x32_bf16(al, b0.v, c0, 0, 0, 0);
            c1 = __builtin_amdgcn_mfma_f32_16x16x32_bf16(ah, b1.v, c1, 0, 0, 0);
            c1 = __builtin_amdgcn_mfma_f32_16x16x32_bf16(am, b1.v, c1, 0, 0, 0);
            c1 = __builtin_amdgcn_mfma_f32_16x16x32_bf16(al, b1.v, c1, 0, 0, 0);
        }
    }

    // psum: reduce across the 16 threads sharing q (lanes xor 1,2,4,8)
    ps += __shfl_xor(ps, 1);
    ps += __shfl_xor(ps, 2);
    ps += __shfl_xor(ps, 4);
    ps += __shfl_xor(ps, 8);
    if ((tid & 15) == 0 && q_glob < QQ)
        atomicAdd(&psum[b * QP + q_glob], ps);

    // C: row(q_local) = quad*4 + r, col(n_local) = lane&15  [m89 layout]
#pragma unroll
    for (int r = 0; r < 4; ++r) {
        int qg = qt * 16 + quad * 4 + r;
        if (qg < QQ) {
            atomicAdd(&inter[(b * NGT + m) * QP + qg],      c0[r]);
            atomicAdd(&inter[(b * NGT + 16 + m) * QP + qg], c1[r]);
        }
    }
}

// ---------------------------------------------------------------------------
// K4: greedy per-GT top-4 with dedup; computes combined = iou*cls on the fly.
// One wave per batch. Matches jax.lax.top_k tie-break (lower index first).
__global__ __launch_bounds__(64) void k_greedy(const float* __restrict__ inter,
                                               const float* __restrict__ psum,
                                               const float* __restrict__ tsum,
                                               const float* __restrict__ cls,
                                               int* __restrict__ out) {
    int b = blockIdx.x;
    int lane = threadIdx.x;
    int* src = out;
    int* tgt = out + BB * NGT * TOPK;
    int* val = out + 2 * BB * NGT * TOPK;

    int asg = 0;  // assigned bits for q = lane + 64*slot
    for (int n = 0; n < NGT; ++n) {
        float tsn = tsum[b * NGT + n];
        float v[4];
#pragma unroll
        for (int s = 0; s < 4; ++s) {
            int q = lane + 64 * s;
            if (q < QQ) {
                float iv = inter[(b * NGT + n) * QP + q];
                float un = psum[b * QP + q] + tsn - iv;
                v[s] = iv / (un + EPSF) * cls[b * QQ + q];
            } else {
                v[s] = -INFINITY;
            }
        }
        for (int k = 0; k < TOPK; ++k) {
            float bv = -INFINITY;
            int   bi = 0x7fffffff;
#pragma unroll
            for (int s = 0; s < 4; ++s)
                if (v[s] > bv) { bv = v[s]; bi = lane + 64 * s; }
#pragma unroll
            for (int off = 32; off; off >>= 1) {
                float ov = __shfl_xor(bv, off);
                int   oi = __shfl_xor(bi, off);
                if (ov > bv || (ov == bv && oi < bi)) { bv = ov; bi = oi; }
            }
            int owner = bi & 63, slot = bi >> 6;
            int oasg  = __shfl(asg, owner);
            int taken = (oasg >> slot) & 1;
#pragma unroll
            for (int s = 0; s < 4; ++s)
                if (lane == owner && s == slot) v[s] = -INFINITY;
            if (lane == owner) asg |= (1 << slot);
            if (lane == 0) {
                int o = (b * NGT + n) * TOPK + k;
                src[o] = taken ? -1 : bi;
                tgt[o] = taken ? -1 : n;
                val[o] = taken ? 0 : 1;
            }
        }
    }
}

// ---------------------------------------------------------------------------
extern "C" void kernel_launch(void* const* d_in, const int* in_sizes, int n_in,
                              void* d_out, int out_size, void* d_ws, size_t ws_size,
                              hipStream_t stream) {
    const float* pred_masks  = (const float*)d_in[0];  // [4,200,256,256]
    const float* pred_logits = (const float*)d_in[1];  // [4,200,2]
    const float* gt_masks    = (const float*)d_in[2];  // [4,32,256,256]

    uint8_t* ws = (uint8_t*)d_ws;
    uint32_t* packed = (uint32_t*)ws;                           // 1 MB
    float* tsum  = (float*)(ws + (size_t)BB * DD * 4);          // 128
    float* inter = tsum + BB * NGT;                             // 26624 (zeroed)
    float* psum  = inter + BB * NGT * QP;                       // 832   (zeroed, contiguous with inter)
    float* cls   = psum + BB * QP;                              // 800

    k_pack<<<BB * (DD / 1024), 256, 0, stream>>>(gt_masks, packed);
    k_tsum<<<BB * NGT, 256, 0, stream>>>(packed, tsum, inter, pred_logits, cls);
    k_mfma<<<BB * QT_ * KSPLIT, 256, 0, stream>>>(pred_masks, packed, inter, psum);
    k_greedy<<<BB, 64, 0, stream>>>(inter, psum, tsum, cls, (int*)d_out);
}

// Round 3
// 369.583 us; speedup vs baseline: 1.5956x; 1.3048x over previous
//
#include <hip/hip_runtime.h>
#include <math.h>
#include <stdint.h>

#define BB    4
#define QQ    200
#define NGT   32
#define DD    65536   // 256*256
#define TOPK  4
#define EPSF  1e-6f
#define QP    208     // padded Q stride

#define QT3   7               // ceil(200/32) q-tiles of 32
#define KS    32              // K-split
#define KC    (DD / KS)       // 2048 k per workgroup
#define BK    128             // staged K chunk
#define NCH   (KC / BK)       // 16 chunks
#define NSTEP (BK / 16)       // 8 16-k steps per chunk
#define BKP   (BK + 8)        // +8 bf16 pad (16B) for LDS bank spread

typedef float  f32x4  __attribute__((ext_vector_type(4)));
typedef float  f32x16 __attribute__((ext_vector_type(16)));
typedef __bf16 bf16x8 __attribute__((ext_vector_type(8)));

// ---------------------------------------------------------------------------
// K1: bit-pack gt_masks -> packed[b][d] (bit n = gt[b,n,d]); fused zero-init
// of inter+psum (ws is poisoned 0xAA before every timed call).
__global__ __launch_bounds__(256) void k_pack(const float* __restrict__ gt,
                                              uint32_t* __restrict__ packed,
                                              float* __restrict__ zero_base) {
    int zidx = blockIdx.x * 256 + threadIdx.x;
    if (zidx < BB * NGT * QP + BB * QP) zero_base[zidx] = 0.0f;

    int blk = blockIdx.x;
    int b = blk >> 6;
    int d0 = ((blk & 63) * 256 + threadIdx.x) * 4;
    uint32_t px = 0, py = 0, pz = 0, pw = 0;
    const float* gb = gt + (size_t)b * NGT * DD + d0;
#pragma unroll
    for (int n = 0; n < NGT; ++n) {
        float4 g = *(const float4*)(gb + (size_t)n * DD);
        px |= (g.x > 0.5f ? 1u : 0u) << n;
        py |= (g.y > 0.5f ? 1u : 0u) << n;
        pz |= (g.z > 0.5f ? 1u : 0u) << n;
        pw |= (g.w > 0.5f ? 1u : 0u) << n;
    }
    *(uint4*)(packed + (size_t)b * DD + d0) = make_uint4(px, py, pz, pw);
}

// ---------------------------------------------------------------------------
// K2: tsum[b][n] via popcount of packed; fused cls = softmax(logits)[...,1].
__global__ __launch_bounds__(256) void k_tsum(const uint32_t* __restrict__ packed,
                                              float* __restrict__ tsum,
                                              const float* __restrict__ logits,
                                              float* __restrict__ cls) {
    if (blockIdx.x < 4) {
        int i = blockIdx.x * 256 + threadIdx.x;
        if (i < BB * QQ) {
            float l0 = logits[2 * i], l1 = logits[2 * i + 1];
            cls[i] = 1.0f / (1.0f + expf(l0 - l1));
        }
    }
    int b = blockIdx.x >> 5;
    int n = blockIdx.x & 31;
    const uint4* pp = (const uint4*)(packed + (size_t)b * DD);
    int cnt = 0;
    for (int i = threadIdx.x; i < DD / 4; i += 256) {
        uint4 w = pp[i];
        cnt += (int)((w.x >> n) & 1u) + (int)((w.y >> n) & 1u) +
               (int)((w.z >> n) & 1u) + (int)((w.w >> n) & 1u);
    }
#pragma unroll
    for (int off = 32; off; off >>= 1) cnt += __shfl_xor(cnt, off);
    __shared__ int red[4];
    if ((threadIdx.x & 63) == 0) red[threadIdx.x >> 6] = cnt;
    __syncthreads();
    if (threadIdx.x == 0)
        tsum[blockIdx.x] = (float)(red[0] + red[1] + red[2] + red[3]);
}

// ---------------------------------------------------------------------------
// K3: MFMA main. 32x32x16 bf16: one MFMA covers all 32 GTs x 32 q.
// Grid = B * QT3 * KS workgroups of 256 (4 waves). Workgroup: 32-q tile,
// 2048-k. Per 128-k chunk: stage A (sigmoid, exact 3-term bf16 split by
// bit-truncation) + build B fragments ONCE cooperatively into LDS; waves
// split the 8 16-k steps (2 each), 3 MFMAs/step (hi/mid/lo, independent
// accumulators). Cross-wave C reduce in LDS -> one atomic set per wg.
__global__ __launch_bounds__(256, 3) void k_mfma(const float* __restrict__ pm,
                                                 const uint32_t* __restrict__ packed,
                                                 float* __restrict__ inter,   // [B][32][QP]
                                                 float* __restrict__ psum) {  // [B][QP]
    int blk = blockIdx.x;
    int b   = blk / (QT3 * KS);
    int rem = blk % (QT3 * KS);
    int qt  = rem / KS;
    int ks  = rem % KS;
    int tid = threadIdx.x, lane = tid & 63, wave = tid >> 6;

    __shared__ __bf16 aA[3][32][BKP];            // hi/mid/lo planes, 25.5 KB
    __shared__ uint32_t bfrag[NSTEP * 256];      // B fragments, 8 KB

    // staging role: 8 threads per q row, 16 consecutive k each
    int q_local = tid >> 3;
    int dseg    = (tid & 7) * 16;
    int q_glob  = qt * 32 + q_local;
    int q_eff   = q_glob < QQ ? q_glob : QQ - 1;
    const float*    pmrow = pm + (size_t)(b * QQ + q_eff) * DD + ks * KC;
    const uint32_t* pk    = packed + (size_t)b * DD + ks * KC;

    // B-build role: thread builds 8 dwords = fragments for lanes l0,l1
    int l0  = (tid * 2) & 63;
    int bst = tid >> 5;                      // step index 0..7
    int bko = bst * 16 + ((l0 >> 5) << 3);   // 8 consecutive words
    int sh0 = 31 - (l0 & 31);
    int sh1 = 31 - ((l0 + 1) & 31);

    // compute role
    int m    = lane & 31;
    int half = lane >> 5;

    f32x16 ch_, cm_, cl_;
#pragma unroll
    for (int r = 0; r < 16; ++r) { ch_[r] = 0.f; cm_[r] = 0.f; cl_[r] = 0.f; }
    float ps = 0.f;

    for (int ch = 0; ch < NCH; ++ch) {
        // ---- A: 16 pixels -> sigmoid -> exact hi/mid/lo bf16 (no LDS yet)
        const float* src = pmrow + ch * BK + dseg;
        float4 f0 = *(const float4*)(src);
        float4 f1 = *(const float4*)(src + 4);
        float4 f2 = *(const float4*)(src + 8);
        float4 f3 = *(const float4*)(src + 12);
        float xv[16] = {f0.x, f0.y, f0.z, f0.w, f1.x, f1.y, f1.z, f1.w,
                        f2.x, f2.y, f2.z, f2.w, f3.x, f3.y, f3.z, f3.w};
        uint32_t hd[8], md[8], ld[8];
#pragma unroll
        for (int p = 0; p < 8; ++p) {
            uint32_t uh[2], um[2], ul[2];
#pragma unroll
            for (int e = 0; e < 2; ++e) {
                float x = xv[2 * p + e];
                float s = __builtin_amdgcn_rcpf(1.0f + __expf(-x));
                ps += s;
                uint32_t u0 = __float_as_uint(s);
                float hi = __uint_as_float(u0 & 0xFFFF0000u);
                float r1 = s - hi;                       // exact
                uint32_t u1 = __float_as_uint(r1);
                float mi = __uint_as_float(u1 & 0xFFFF0000u);
                float r2 = r1 - mi;                      // exact, <=8 sig bits
                uh[e] = u0; um[e] = u1; ul[e] = __float_as_uint(r2);
            }
            hd[p] = (uh[0] >> 16) | (uh[1] & 0xFFFF0000u);
            md[p] = (um[0] >> 16) | (um[1] & 0xFFFF0000u);
            ld[p] = (ul[0] >> 16) | (ul[1] & 0xFFFF0000u);
        }
        // ---- B fragments: 8 dwords/thread from 8 packed words (shared l0/l1)
        uint4 wa = *(const uint4*)(pk + ch * BK + bko);
        uint4 wb = *(const uint4*)(pk + ch * BK + bko + 4);
        uint32_t w[8] = {wa.x, wa.y, wa.z, wa.w, wb.x, wb.y, wb.z, wb.w};
        uint32_t bv[8];
#pragma unroll
        for (int dw = 0; dw < 4; ++dw) {
            bv[dw]     = (uint32_t)(((int)(w[2 * dw] << sh0) >> 31) & 0x3F80)
                       | (uint32_t)(((int)(w[2 * dw + 1] << sh0) >> 31) & 0x3F800000);
            bv[4 + dw] = (uint32_t)(((int)(w[2 * dw] << sh1) >> 31) & 0x3F80)
                       | (uint32_t)(((int)(w[2 * dw + 1] << sh1) >> 31) & 0x3F800000);
        }

        __syncthreads();   // previous chunk's LDS reads complete
        *(uint4*)&aA[0][q_local][dseg]     = make_uint4(hd[0], hd[1], hd[2], hd[3]);
        *(uint4*)&aA[0][q_local][dseg + 8] = make_uint4(hd[4], hd[5], hd[6], hd[7]);
        *(uint4*)&aA[1][q_local][dseg]     = make_uint4(md[0], md[1], md[2], md[3]);
        *(uint4*)&aA[1][q_local][dseg + 8] = make_uint4(md[4], md[5], md[6], md[7]);
        *(uint4*)&aA[2][q_local][dseg]     = make_uint4(ld[0], ld[1], ld[2], ld[3]);
        *(uint4*)&aA[2][q_local][dseg + 8] = make_uint4(ld[4], ld[5], ld[6], ld[7]);
        *(uint4*)&bfrag[tid * 8]     = make_uint4(bv[0], bv[1], bv[2], bv[3]);
        *(uint4*)&bfrag[tid * 8 + 4] = make_uint4(bv[4], bv[5], bv[6], bv[7]);
        __syncthreads();

        // ---- compute: wave w takes steps {2w, 2w+1}
#pragma unroll
        for (int st = 0; st < 2; ++st) {
            int sidx = wave * 2 + st;
            int k0 = sidx * 16 + half * 8;
            bf16x8 ah = *(const bf16x8*)&aA[0][m][k0];
            bf16x8 am = *(const bf16x8*)&aA[1][m][k0];
            bf16x8 al = *(const bf16x8*)&aA[2][m][k0];
            bf16x8 bb = *(const bf16x8*)&bfrag[sidx * 256 + lane * 4];
            ch_ = __builtin_amdgcn_mfma_f32_32x32x16_bf16(ah, bb, ch_, 0, 0, 0);
            cm_ = __builtin_amdgcn_mfma_f32_32x32x16_bf16(am, bb, cm_, 0, 0, 0);
            cl_ = __builtin_amdgcn_mfma_f32_32x32x16_bf16(al, bb, cl_, 0, 0, 0);
        }
    }

    // psum: reduce across the 8 threads sharing a q row
    ps += __shfl_xor(ps, 1);
    ps += __shfl_xor(ps, 2);
    ps += __shfl_xor(ps, 4);
    if ((tid & 7) == 0 && q_glob < QQ) atomicAdd(&psum[b * QP + q_glob], ps);

    // merge terms, cross-wave reduce in LDS, one atomic set per wg
    f32x16 c;
#pragma unroll
    for (int r = 0; r < 16; ++r) c[r] = ch_[r] + cm_[r] + cl_[r];

    __syncthreads();
    float* cred = (float*)aA;   // 12 KB needed, 25.5 KB available
    if (wave > 0) {
        float* dst = cred + ((size_t)(wave - 1) * 64 + lane) * 16;
#pragma unroll
        for (int r = 0; r < 16; r += 4) {
            f32x4 v = {c[r], c[r + 1], c[r + 2], c[r + 3]};
            *(f32x4*)(dst + r) = v;
        }
    }
    __syncthreads();
    if (wave == 0) {
#pragma unroll
        for (int wv = 0; wv < 3; ++wv) {
            const float* sp = cred + ((size_t)wv * 64 + lane) * 16;
#pragma unroll
            for (int r = 0; r < 16; ++r) c[r] += sp[r];
        }
        int n = lane & 31;
#pragma unroll
        for (int r = 0; r < 16; ++r) {
            int qg = qt * 32 + (r & 3) + 8 * (r >> 2) + 4 * half;
            if (qg < QQ) atomicAdd(&inter[(b * NGT + n) * QP + qg], c[r]);
        }
    }
}

// ---------------------------------------------------------------------------
// K4: parallel top-4 per (b,n): 128 wgs of 64. combined computed on the fly.
__global__ __launch_bounds__(64) void k_topk(const float* __restrict__ inter,
                                             const float* __restrict__ psum,
                                             const float* __restrict__ tsum,
                                             const float* __restrict__ cls,
                                             int* __restrict__ idx4) {
    int bn = blockIdx.x;            // b*32 + n
    int b  = bn >> 5;
    int lane = threadIdx.x;
    float tsn = tsum[bn];
    float v[4];
#pragma unroll
    for (int s = 0; s < 4; ++s) {
        int q = lane + 64 * s;
        if (q < QQ) {
            float iv = inter[(size_t)bn * QP + q];
            float un = psum[b * QP + q] + tsn - iv;
            v[s] = iv / (un + EPSF) * cls[b * QQ + q];
        } else {
            v[s] = -INFINITY;
        }
    }
    for (int k = 0; k < TOPK; ++k) {
        float bv = -INFINITY;
        int   bi = 0x7fffffff;
#pragma unroll
        for (int s = 0; s < 4; ++s)
            if (v[s] > bv) { bv = v[s]; bi = lane + 64 * s; }
#pragma unroll
        for (int off = 32; off; off >>= 1) {
            float ov = __shfl_xor(bv, off);
            int   oi = __shfl_xor(bi, off);
            if (ov > bv || (ov == bv && oi < bi)) { bv = ov; bi = oi; }
        }
        if (lane == (bi & 63)) v[bi >> 6] = -INFINITY;
        if (lane == 0) idx4[bn * TOPK + k] = bi;
    }
}

// ---------------------------------------------------------------------------
// K5: sequential dedup over GTs (cheap: indices precomputed). One wave per b.
__global__ __launch_bounds__(64) void k_final(const int* __restrict__ idx4,
                                              int* __restrict__ out) {
    int b = blockIdx.x;
    int lane = threadIdx.x;
    int* src = out;
    int* tgt = out + BB * NGT * TOPK;
    int* val = out + 2 * BB * NGT * TOPK;
    int asg = 0;   // 4 assigned bits: q = lane + 64*slot
    for (int n = 0; n < NGT; ++n) {
        int4 id = *(const int4*)&idx4[(b * NGT + n) * TOPK];
        int ids[4] = {id.x, id.y, id.z, id.w};
        int newasg = asg;
#pragma unroll
        for (int k = 0; k < TOPK; ++k) {
            int idx = ids[k];                      // uniform across lanes
            int owner = idx & 63, slot = idx >> 6;
            int oasg = __shfl(asg, owner);         // pre-n state (idx distinct in n)
            int taken = (oasg >> slot) & 1;
            if (lane == owner) newasg |= (1 << slot);
            if (lane == 0) {
                int o = (b * NGT + n) * TOPK + k;
                src[o] = taken ? -1 : idx;
                tgt[o] = taken ? -1 : n;
                val[o] = taken ? 0 : 1;
            }
        }
        asg = newasg;
    }
}

// ---------------------------------------------------------------------------
extern "C" void kernel_launch(void* const* d_in, const int* in_sizes, int n_in,
                              void* d_out, int out_size, void* d_ws, size_t ws_size,
                              hipStream_t stream) {
    const float* pred_masks  = (const float*)d_in[0];  // [4,200,256,256]
    const float* pred_logits = (const float*)d_in[1];  // [4,200,2]
    const float* gt_masks    = (const float*)d_in[2];  // [4,32,256,256]

    uint8_t* ws = (uint8_t*)d_ws;
    uint32_t* packed = (uint32_t*)ws;                   // 1 MB
    float* tsum  = (float*)(ws + (size_t)BB * DD * 4);  // 128
    float* inter = tsum + BB * NGT;                     // 26624 (zeroed by k_pack)
    float* psum  = inter + BB * NGT * QP;               // 832   (zeroed, contiguous)
    float* cls   = psum + BB * QP;                      // 800
    int*   idx4  = (int*)(cls + BB * QQ);               // 512

    k_pack <<<BB * (DD / 1024), 256, 0, stream>>>(gt_masks, packed, inter);
    k_tsum <<<BB * NGT,         256, 0, stream>>>(packed, tsum, pred_logits, cls);
    k_mfma <<<BB * QT3 * KS,    256, 0, stream>>>(pred_masks, packed, inter, psum);
    k_topk <<<BB * NGT,          64, 0, stream>>>(inter, psum, tsum, cls, idx4);
    k_final<<<BB,                64, 0, stream>>>(idx4, (int*)d_out);
}